// Round 12
// baseline (34.068 us; speedup 1.0000x reference)
//
#include <hip/hip_runtime.h>
#include <hip/hip_bf16.h>

// Problem constants (from reference)
#define KK 2
#define BB 4
#define VV 2000
#define DD 64
#define HH 4
#define DHH 64
#define PP 128
#define ALPHA_ 0.2f

// k_attn geometry: 16-row tiles (1 MFMA row-tile per block) for 2 blocks/CU
#define RPT 16                // rows per tile
#define YT  16                // y-blocks (tiles strided by YT)

typedef __attribute__((ext_vector_type(8))) short bf16x8;
typedef __attribute__((ext_vector_type(4))) float f32x4;

__device__ __forceinline__ float lrelu(float z) { return fmaxf(z, ALPHA_ * z); }
__device__ __forceinline__ float elu_(float z)  { return z > 0.f ? z : expm1f(z); }
__device__ __forceinline__ short f2bf(float f) {
  __hip_bfloat16 h = __float2bfloat16(f);
  return *reinterpret_cast<short*>(&h);
}

// ---------------------------------------------------------------------------
// Workspace layout (float offsets):
//   EW  [H][V][DH]   : 0        (512000)
//   F1  [H][V]       : 512000   (8000)
//   F2  [H][V]       : 520000   (8000)
//   LAT [K][B][256]  : 528000   (2048)
//   CNT (int)[8]     : 530048   (8)
//   S   (int)[K*B][V]: 530056   (16000)
// ---------------------------------------------------------------------------
#define OFF_EW   0
#define OFF_F1   512000
#define OFF_F2   520000
#define OFF_LAT  528000
#define OFF_CNT  530048
#define OFF_S    530056

// ---- kernel 0 (fused): EW/F1/F2 precompute (present rows only) + compaction
__global__ __launch_bounds__(256) void k_pre(
    const float* __restrict__ E, const float* __restrict__ W,
    const float* __restrict__ a1, const float* __restrict__ a2,
    const float* __restrict__ x,
    float* __restrict__ EW, float* __restrict__ F1, float* __restrict__ F2,
    int* __restrict__ S, int* __restrict__ cnt, float* __restrict__ lat) {
  const int bid = blockIdx.x;
  const int wave = threadIdx.x >> 6, lane = threadIdx.x & 63;
  if (bid < 2000) {
    const int h = bid / 500;                 // h-major: W_h stays L1-hot
    const int v = (bid % 500) * 4 + wave;
    bool pres = false;                       // skip rows absent in all slices
#pragma unroll
    for (int kb = 0; kb < KK * BB; ++kb) pres |= (x[kb * VV + v] > 0.f);
    if (!pres) return;
    const float* Wh = W + h * DD * DHH;
    const float* Ev = E + v * DD;
    float acc = 0.f;
#pragma unroll 8
    for (int d = 0; d < DD; ++d) acc = fmaf(Ev[d], Wh[d * DHH + lane], acc);
    EW[(size_t)(h * VV + v) * DHH + lane] = acc;
    float r1 = acc * a1[h * DHH + lane];
    float r2 = acc * a2[h * DHH + lane];
#pragma unroll
    for (int s = 32; s; s >>= 1) { r1 += __shfl_xor(r1, s); r2 += __shfl_xor(r2, s); }
    if (lane == 0) { F1[h * VV + v] = r1; F2[h * VV + v] = r2; }
  } else {
    if (wave != 0) return;
    const int kb = bid - 2000;  // 0..7
    for (int i = lane; i < 256; i += 64) lat[kb * 256 + i] = 0.f;
    const float* xr = x + kb * VV;
    int base = 0;
    for (int t = 0; t * 64 < VV; ++t) {
      const int v = t * 64 + lane;
      const bool f = (v < VV) && (xr[v] > 0.f);
      const unsigned long long m = __ballot(f);
      if (f) S[kb * VV + base + __popcll(m & ((1ull << lane) - 1ull))] = v;
      base += __popcll(m);
    }
    if (lane == 0) cnt[kb] = base;
  }
}

// ---- kernel 1: attention rows via MFMA, 16-row tiles ----------------------
// block = (kb, tile, h), 512 blocks -> 2 blocks/CU (2 waves/SIMD latency
// hiding). Wave w owns cols 16w..16w+16 of all 16 rows; stats waves own 4
// rows each. Fire-and-forget atomicMax into lat; dispatch boundary makes
// results visible to k_final.
__global__ __launch_bounds__(256) void k_attn(
    const float* __restrict__ EW, const float* __restrict__ F1,
    const float* __restrict__ F2, const int* __restrict__ S,
    const int* __restrict__ cnt, float* __restrict__ lat) {
  __shared__ int   Sl[2048];     // compacted indices (padded)
  __shared__ float G2l[2048];    // gathered F2 (padded with 0)
  __shared__ float SF1[RPT], SM[RPT], SIV[RPT];

  const int kb = blockIdx.x;     // 0..7
  const int h  = blockIdx.z;     // 0..3
  const int tid = threadIdx.x;
  const int wave = tid >> 6, lane = tid & 63;
  const int n = cnt[kb];
  const int nt = (n + RPT - 1) / RPT;
  if ((int)blockIdx.y >= nt) return;
  const int nup = (n + 31) & ~31;

  const int* Skb = S + kb * VV;
  const float* F2h = F2 + h * VV;
  const float* F1h = F1 + h * VV;
  const float* EWh = EW + (size_t)h * VV * DHH;

  // stage indices + gathered F2 once per block
  for (int j = tid; j < nup; j += 256) {
    const int v = (j < n) ? Skb[j] : Skb[0];
    Sl[j] = v;
    G2l[j] = (j < n) ? F2h[v] : 0.f;
  }
  __syncthreads();

  const int col = (wave << 4) | (lane & 15);   // output/B column
  const int q   = lane >> 4;                   // K-quarter
  const float* EWcol = EWh + col;

  for (int tile = blockIdx.y; tile < nt; tile += YT) {
    // ---- softmax stats: wave owns rows r0w..r0w+4 ----
    const int r0w = tile * RPT + wave * 4;
    bool act[4]; float f1r[4];
#pragma unroll
    for (int i = 0; i < 4; ++i) {
      const int r = r0w + i;
      act[i] = r < n;
      f1r[i] = F1h[Sl[act[i] ? r : 0]];   // wave-uniform gather
    }
    float m[4];
#pragma unroll
    for (int i = 0; i < 4; ++i) m[i] = -3.4e38f;
    for (int jb = lane; jb < n; jb += 64) {
      const float g = G2l[jb];
#pragma unroll
      for (int i = 0; i < 4; ++i) m[i] = fmaxf(m[i], lrelu(f1r[i] + g));
    }
#pragma unroll
    for (int s = 32; s; s >>= 1)
#pragma unroll
      for (int i = 0; i < 4; ++i) m[i] = fmaxf(m[i], __shfl_xor(m[i], s));
    float sm[4];
#pragma unroll
    for (int i = 0; i < 4; ++i) sm[i] = 0.f;
    for (int jb = lane; jb < n; jb += 64) {
      const float g = G2l[jb];
#pragma unroll
      for (int i = 0; i < 4; ++i) sm[i] += __expf(lrelu(f1r[i] + g) - m[i]);
    }
#pragma unroll
    for (int s = 32; s; s >>= 1)
#pragma unroll
      for (int i = 0; i < 4; ++i) sm[i] += __shfl_xor(sm[i], s);

    __syncthreads();  // previous tile's MFMA phase done reading stats
    if (lane == 0) {
#pragma unroll
      for (int i = 0; i < 4; ++i) {
        SF1[wave * 4 + i] = f1r[i];
        SM[wave * 4 + i]  = m[i];
        SIV[wave * 4 + i] = act[i] ? (1.f / sm[i]) : 0.f;
      }
    }
    __syncthreads();  // stats visible to all waves

    // ---- MFMA PV: wave w computes cols 16w..16w+16 of rows 0..15 ----
    const int rl = lane & 15;
    const float f1a = SF1[rl], ma = SM[rl], ia = SIV[rl];
    f32x4 acc0 = {0.f, 0.f, 0.f, 0.f};
    for (int kc = 0; kc < nup; kc += 32) {
      const int kq = kc + q * 8;
      const int4 va = *reinterpret_cast<const int4*>(&Sl[kq]);
      const int4 vb = *reinterpret_cast<const int4*>(&Sl[kq + 4]);
      const float4 ga = *reinterpret_cast<const float4*>(&G2l[kq]);
      const float4 gb = *reinterpret_cast<const float4*>(&G2l[kq + 4]);
      float bv[8];
      bv[0] = EWcol[(size_t)va.x * DHH];
      bv[1] = EWcol[(size_t)va.y * DHH];
      bv[2] = EWcol[(size_t)va.z * DHH];
      bv[3] = EWcol[(size_t)va.w * DHH];
      bv[4] = EWcol[(size_t)vb.x * DHH];
      bv[5] = EWcol[(size_t)vb.y * DHH];
      bv[6] = EWcol[(size_t)vb.z * DHH];
      bv[7] = EWcol[(size_t)vb.w * DHH];
      const float g[8] = {ga.x, ga.y, ga.z, ga.w, gb.x, gb.y, gb.z, gb.w};
      float pa[8];
#pragma unroll
      for (int t = 0; t < 8; ++t)
        pa[t] = __expf(lrelu(f1a + g[t]) - ma) * ia;
      if (kc + 32 > n) {  // K-tail: zero out-of-range columns
#pragma unroll
        for (int t = 0; t < 8; ++t)
          if (kq + t >= n) pa[t] = 0.f;
      }
      bf16x8 A0, Bf;
#pragma unroll
      for (int t = 0; t < 8; ++t) {
        A0[t] = f2bf(pa[t]);
        Bf[t] = f2bf(bv[t]);
      }
      acc0 = __builtin_amdgcn_mfma_f32_16x16x32_bf16(A0, Bf, acc0, 0, 0, 0);
    }
    // epilogue: lat[col] = max(0, max_rows elu(out)) — only positives matter
    float vmax = -3.4e38f;
#pragma unroll
    for (int r = 0; r < 4; ++r) {
      const int row0 = tile * RPT + (q << 2) + r;
      if (row0 < n) vmax = fmaxf(vmax, acc0[r]);
    }
    if (vmax > 0.f)
      atomicMax(reinterpret_cast<int*>(&lat[kb * 256 + h * DHH + col]),
                __float_as_int(vmax));
  }
}

// ---- kernel 2: latent pooling + dense head; one block per batch -----------
// 8-accumulator / 2-way f-split matvec (~32 loads in flight, depth 128).
__global__ __launch_bounds__(256) void k_final(
    const float* __restrict__ cls_w, const float* __restrict__ ac1,
    const float* __restrict__ ac2, const float* __restrict__ dW,
    const float* __restrict__ db, const float* __restrict__ lat,
    float* __restrict__ out) {
  const int b = blockIdx.x;
  const int tid = threadIdx.x;  // 256
  const int lane = tid & 63, wave = tid >> 6;
  __shared__ float pooled[256];
  __shared__ float finp[2][PP];
  __shared__ float red[4][4];
  const float cw = cls_w[tid];
  const float l0 = lat[(0 * BB + b) * 256 + tid];
  const float l1 = lat[(1 * BB + b) * 256 + tid];
  float t0 = cw * ac1[tid];
  float t1 = cw * ac2[tid];
  float t2 = l0 * ac2[tid];
  float t3 = l1 * ac2[tid];
#pragma unroll
  for (int s = 32; s; s >>= 1) {
    t0 += __shfl_xor(t0, s); t1 += __shfl_xor(t1, s);
    t2 += __shfl_xor(t2, s); t3 += __shfl_xor(t3, s);
  }
  if (lane == 0) { red[wave][0] = t0; red[wave][1] = t1; red[wave][2] = t2; red[wave][3] = t3; }
  __syncthreads();
  const float ca1 = red[0][0] + red[1][0] + red[2][0] + red[3][0];
  const float d0  = red[0][1] + red[1][1] + red[2][1] + red[3][1];
  const float d1  = red[0][2] + red[1][2] + red[2][2] + red[3][2];
  const float d2  = red[0][3] + red[1][3] + red[2][3] + red[3][3];
  const float e0 = lrelu(ca1 + d0), e1 = lrelu(ca1 + d1), e2 = lrelu(ca1 + d2);
  const float mm = fmaxf(e0, fmaxf(e1, e2));
  const float x0 = __expf(e0 - mm), x1 = __expf(e1 - mm), x2 = __expf(e2 - mm);
  const float invs = 1.f / (x0 + x1 + x2);
  pooled[tid] = (x0 * cw + x1 * l0 + x2 * l1) * invs;
  __syncthreads();
  {  // dense head: f-dim split 2-way, 8 accumulators
    const int o = tid & (PP - 1), half = tid >> 7;
    const float* dWc = dW + (half * 128) * PP + o;
    const float* pl = &pooled[half * 128];
    float a0 = 0.f, b1 = 0.f, b2 = 0.f, b3 = 0.f;
    float a4 = 0.f, a5 = 0.f, a6 = 0.f, a7 = 0.f;
#pragma unroll
    for (int f = 0; f < 128; f += 8) {
      a0 = fmaf(pl[f + 0], dWc[(f + 0) * PP], a0);
      b1 = fmaf(pl[f + 1], dWc[(f + 1) * PP], b1);
      b2 = fmaf(pl[f + 2], dWc[(f + 2) * PP], b2);
      b3 = fmaf(pl[f + 3], dWc[(f + 3) * PP], b3);
      a4 = fmaf(pl[f + 4], dWc[(f + 4) * PP], a4);
      a5 = fmaf(pl[f + 5], dWc[(f + 5) * PP], a5);
      a6 = fmaf(pl[f + 6], dWc[(f + 6) * PP], a6);
      a7 = fmaf(pl[f + 7], dWc[(f + 7) * PP], a7);
    }
    finp[half][o] = ((a0 + b1) + (b2 + b3)) + ((a4 + a5) + (a6 + a7));
  }
  __syncthreads();
  if (tid < PP) out[b * PP + tid] = elu_(db[tid] + finp[0][tid] + finp[1][tid]);
}

extern "C" void kernel_launch(void* const* d_in, const int* in_sizes, int n_in,
                              void* d_out, int out_size, void* d_ws, size_t ws_size,
                              hipStream_t stream) {
  const float* x     = (const float*)d_in[0];
  const float* E     = (const float*)d_in[1];
  const float* W     = (const float*)d_in[2];
  const float* a1    = (const float*)d_in[3];
  const float* a2    = (const float*)d_in[4];
  const float* cls_w = (const float*)d_in[5];
  const float* ac1   = (const float*)d_in[6];
  const float* ac2   = (const float*)d_in[7];
  const float* dW    = (const float*)d_in[8];
  const float* db    = (const float*)d_in[9];
  float* out = (float*)d_out;

  float* ws  = (float*)d_ws;
  float* EW  = ws + OFF_EW;
  float* F1  = ws + OFF_F1;
  float* F2  = ws + OFF_F2;
  float* LAT = ws + OFF_LAT;
  int*   CNT = (int*)(ws + OFF_CNT);
  int*   S   = (int*)(ws + OFF_S);

  k_pre<<<2008, 256, 0, stream>>>(E, W, a1, a2, x, EW, F1, F2, S, CNT, LAT);
  k_attn<<<dim3(KK * BB, YT, HH), 256, 0, stream>>>(EW, F1, F2, S, CNT, LAT);
  k_final<<<BB, 256, 0, stream>>>(cls_w, ac1, ac2, dW, db, LAT, out);
}

// Round 13
// 30.129 us; speedup vs baseline: 1.1308x; 1.1308x over previous
//
#include <hip/hip_runtime.h>
#include <hip/hip_bf16.h>

// Problem constants (from reference)
#define KK 2
#define BB 4
#define VV 2000
#define DD 64
#define HH 4
#define DHH 64
#define PP 128
#define ALPHA_ 0.2f

// k_attn geometry (R5-validated): 32-row tiles, grid (8,8,4) = 256 blocks
#define RPB 32                // rows per block-tile (2 MFMA row-tiles)
#define YB  8                 // y-blocks (tiles strided by YB)

typedef __attribute__((ext_vector_type(8))) short bf16x8;
typedef __attribute__((ext_vector_type(4))) float f32x4;

__device__ __forceinline__ float lrelu(float z) { return fmaxf(z, ALPHA_ * z); }
__device__ __forceinline__ float elu_(float z)  { return z > 0.f ? z : expm1f(z); }
__device__ __forceinline__ short f2bf(float f) {
  __hip_bfloat16 h = __float2bfloat16(f);
  return *reinterpret_cast<short*>(&h);
}

// ---------------------------------------------------------------------------
// Workspace layout (float offsets):
//   EW  [H][V][DH]   : 0        (512000)
//   F1  [H][V]       : 512000   (8000)
//   F2  [H][V]       : 520000   (8000)
//   LAT [K][B][256]  : 528000   (2048)
//   CNT (int)[8]     : 530048   (8)
//   S   (int)[K*B][V]: 530056   (16000)
// ---------------------------------------------------------------------------
#define OFF_EW   0
#define OFF_F1   512000
#define OFF_F2   520000
#define OFF_LAT  528000
#define OFF_CNT  530048
#define OFF_S    530056

// ---- kernel 0 (fused): EW/F1/F2 precompute (present rows only) + compaction
__global__ __launch_bounds__(256) void k_pre(
    const float* __restrict__ E, const float* __restrict__ W,
    const float* __restrict__ a1, const float* __restrict__ a2,
    const float* __restrict__ x,
    float* __restrict__ EW, float* __restrict__ F1, float* __restrict__ F2,
    int* __restrict__ S, int* __restrict__ cnt, float* __restrict__ lat) {
  const int bid = blockIdx.x;
  const int wave = threadIdx.x >> 6, lane = threadIdx.x & 63;
  if (bid < 2000) {
    const int h = bid / 500;                 // h-major: W_h stays L1-hot
    const int v = (bid % 500) * 4 + wave;
    bool pres = false;                       // skip rows absent in all slices
#pragma unroll
    for (int kb = 0; kb < KK * BB; ++kb) pres |= (x[kb * VV + v] > 0.f);
    if (!pres) return;
    const float* Wh = W + h * DD * DHH;
    const float* Ev = E + v * DD;
    float acc = 0.f;
#pragma unroll 8
    for (int d = 0; d < DD; ++d) acc = fmaf(Ev[d], Wh[d * DHH + lane], acc);
    EW[(size_t)(h * VV + v) * DHH + lane] = acc;
    float r1 = acc * a1[h * DHH + lane];
    float r2 = acc * a2[h * DHH + lane];
#pragma unroll
    for (int s = 32; s; s >>= 1) { r1 += __shfl_xor(r1, s); r2 += __shfl_xor(r2, s); }
    if (lane == 0) { F1[h * VV + v] = r1; F2[h * VV + v] = r2; }
  } else {
    if (wave != 0) return;
    const int kb = bid - 2000;  // 0..7
    for (int i = lane; i < 256; i += 64) lat[kb * 256 + i] = 0.f;
    const float* xr = x + kb * VV;
    int base = 0;
    for (int t = 0; t * 64 < VV; ++t) {
      const int v = t * 64 + lane;
      const bool f = (v < VV) && (xr[v] > 0.f);
      const unsigned long long m = __ballot(f);
      if (f) S[kb * VV + base + __popcll(m & ((1ull << lane) - 1ull))] = v;
      base += __popcll(m);
    }
    if (lane == 0) cnt[kb] = base;
  }
}

// ---- kernel 1: attention rows via MFMA (R5-validated, byte-identical) -----
// block = (kb, tile-stride y, h); 32 rows per tile. Softmax stats in f32
// (wave w owns rows 8w..8w+8), then PV as bf16 MFMA 16x16x32:
//   A = P (computed per-lane in registers), B = EW columns (L2 gathers).
__global__ __launch_bounds__(256) void k_attn(
    const float* __restrict__ EW, const float* __restrict__ F1,
    const float* __restrict__ F2, const int* __restrict__ S,
    const int* __restrict__ cnt, float* __restrict__ lat) {
  __shared__ int   Sl[2048];     // compacted indices (padded)
  __shared__ float G2l[2048];    // gathered F2 (padded with 0)
  __shared__ float G1l[2048];    // gathered F1
  __shared__ float SF1[RPB], SM[RPB], SIV[RPB];  // per-tile row stats

  const int kb = blockIdx.x;     // 0..7
  const int h  = blockIdx.z;     // 0..3
  const int tid = threadIdx.x;
  const int wave = tid >> 6, lane = tid & 63;
  const int n = cnt[kb];
  const int nt = (n + RPB - 1) / RPB;
  if ((int)blockIdx.y >= nt) return;
  const int nup = (n + 31) & ~31;

  const int* Skb = S + kb * VV;
  const float* F2h = F2 + h * VV;
  const float* F1h = F1 + h * VV;
  const float* EWh = EW + (size_t)h * VV * DHH;

  // stage indices + gathered F1/F2 once per block
  for (int j = tid; j < nup; j += 256) {
    const int v = (j < n) ? Skb[j] : Skb[0];
    Sl[j] = v;
    G2l[j] = (j < n) ? F2h[v] : 0.f;
    G1l[j] = F1h[v];
  }
  __syncthreads();

  const int col = (wave << 4) | (lane & 15);   // output/B column
  const int q   = lane >> 4;                   // K-quarter
  const float* EWcol = EWh + col;

  for (int tile = blockIdx.y; tile < nt; tile += YB) {
    // ---- softmax stats: wave owns rows r0w..r0w+8 ----
    const int r0w = tile * RPB + wave * 8;
    bool act[8]; float f1r[8];
#pragma unroll
    for (int i = 0; i < 8; ++i) {
      const int r = r0w + i;
      act[i] = r < n;
      f1r[i] = G1l[act[i] ? r : 0];
    }
    float m[8];
#pragma unroll
    for (int i = 0; i < 8; ++i) m[i] = -3.4e38f;
    for (int jb = lane; jb < n; jb += 64) {
      const float g = G2l[jb];
#pragma unroll
      for (int i = 0; i < 8; ++i) m[i] = fmaxf(m[i], lrelu(f1r[i] + g));
    }
#pragma unroll
    for (int s = 32; s; s >>= 1)
#pragma unroll
      for (int i = 0; i < 8; ++i) m[i] = fmaxf(m[i], __shfl_xor(m[i], s));
    float sm[8];
#pragma unroll
    for (int i = 0; i < 8; ++i) sm[i] = 0.f;
    for (int jb = lane; jb < n; jb += 64) {
      const float g = G2l[jb];
#pragma unroll
      for (int i = 0; i < 8; ++i) sm[i] += __expf(lrelu(f1r[i] + g) - m[i]);
    }
#pragma unroll
    for (int s = 32; s; s >>= 1)
#pragma unroll
      for (int i = 0; i < 8; ++i) sm[i] += __shfl_xor(sm[i], s);

    __syncthreads();  // previous tile's MFMA phase done reading stats
    if (lane == 0) {
#pragma unroll
      for (int i = 0; i < 8; ++i) {
        SF1[wave * 8 + i] = f1r[i];
        SM[wave * 8 + i]  = m[i];
        SIV[wave * 8 + i] = act[i] ? (1.f / sm[i]) : 0.f;
      }
    }
    __syncthreads();  // stats visible to all waves

    // ---- MFMA PV phase: wave w computes cols 16w..16w+16, rows 0..31 ----
    const int rl = lane & 15;
    const float f1a = SF1[rl],      ma = SM[rl],      ia = SIV[rl];
    const float f1b = SF1[16 + rl], mb = SM[16 + rl], ib = SIV[16 + rl];
    f32x4 acc0 = {0.f, 0.f, 0.f, 0.f}, acc1 = {0.f, 0.f, 0.f, 0.f};
    for (int kc = 0; kc < nup; kc += 32) {
      const int kq = kc + q * 8;
      const int4 va = *reinterpret_cast<const int4*>(&Sl[kq]);
      const int4 vb = *reinterpret_cast<const int4*>(&Sl[kq + 4]);
      const float4 ga = *reinterpret_cast<const float4*>(&G2l[kq]);
      const float4 gb = *reinterpret_cast<const float4*>(&G2l[kq + 4]);
      float bv[8];
      bv[0] = EWcol[(size_t)va.x * DHH];
      bv[1] = EWcol[(size_t)va.y * DHH];
      bv[2] = EWcol[(size_t)va.z * DHH];
      bv[3] = EWcol[(size_t)va.w * DHH];
      bv[4] = EWcol[(size_t)vb.x * DHH];
      bv[5] = EWcol[(size_t)vb.y * DHH];
      bv[6] = EWcol[(size_t)vb.z * DHH];
      bv[7] = EWcol[(size_t)vb.w * DHH];
      const float g[8] = {ga.x, ga.y, ga.z, ga.w, gb.x, gb.y, gb.z, gb.w};
      float pa[8], pb[8];
#pragma unroll
      for (int t = 0; t < 8; ++t) {
        const float gt = g[t];
        pa[t] = __expf(lrelu(f1a + gt) - ma) * ia;
        pb[t] = __expf(lrelu(f1b + gt) - mb) * ib;
      }
      if (kc + 32 > n) {  // K-tail: zero out-of-range columns
#pragma unroll
        for (int t = 0; t < 8; ++t)
          if (kq + t >= n) { pa[t] = 0.f; pb[t] = 0.f; }
      }
      bf16x8 A0, A1, Bf;
#pragma unroll
      for (int t = 0; t < 8; ++t) {
        A0[t] = f2bf(pa[t]);
        A1[t] = f2bf(pb[t]);
        Bf[t] = f2bf(bv[t]);
      }
      acc0 = __builtin_amdgcn_mfma_f32_16x16x32_bf16(A0, Bf, acc0, 0, 0, 0);
      acc1 = __builtin_amdgcn_mfma_f32_16x16x32_bf16(A1, Bf, acc1, 0, 0, 0);
    }
    // ---- epilogue: lat[col] = max(0, max_rows elu(out)) ----
    float vmax = -3.4e38f;
#pragma unroll
    for (int r = 0; r < 4; ++r) {
      const int row0 = tile * RPB + (q << 2) + r;
      const int row1 = row0 + 16;
      if (row0 < n) vmax = fmaxf(vmax, acc0[r]);
      if (row1 < n) vmax = fmaxf(vmax, acc1[r]);
    }
    if (vmax > 0.f)
      atomicMax(reinterpret_cast<int*>(&lat[kb * 256 + h * DHH + col]),
                __float_as_int(vmax));
  }
}

// ---- kernel 2: latent pooling + dense head; one block per batch -----------
// 8-accumulator / 2-way f-split matvec (~32 loads in flight, depth 128) —
// R9-validated replacement for the 256-deep serial chain.
__global__ __launch_bounds__(256) void k_final(
    const float* __restrict__ cls_w, const float* __restrict__ ac1,
    const float* __restrict__ ac2, const float* __restrict__ dW,
    const float* __restrict__ db, const float* __restrict__ lat,
    float* __restrict__ out) {
  const int b = blockIdx.x;
  const int tid = threadIdx.x;  // 256
  const int lane = tid & 63, wave = tid >> 6;
  __shared__ float pooled[256];
  __shared__ float finp[2][PP];
  __shared__ float red[4][4];
  const float cw = cls_w[tid];
  const float l0 = lat[(0 * BB + b) * 256 + tid];
  const float l1 = lat[(1 * BB + b) * 256 + tid];
  float t0 = cw * ac1[tid];
  float t1 = cw * ac2[tid];
  float t2 = l0 * ac2[tid];
  float t3 = l1 * ac2[tid];
#pragma unroll
  for (int s = 32; s; s >>= 1) {
    t0 += __shfl_xor(t0, s); t1 += __shfl_xor(t1, s);
    t2 += __shfl_xor(t2, s); t3 += __shfl_xor(t3, s);
  }
  if (lane == 0) { red[wave][0] = t0; red[wave][1] = t1; red[wave][2] = t2; red[wave][3] = t3; }
  __syncthreads();
  const float ca1 = red[0][0] + red[1][0] + red[2][0] + red[3][0];
  const float d0  = red[0][1] + red[1][1] + red[2][1] + red[3][1];
  const float d1  = red[0][2] + red[1][2] + red[2][2] + red[3][2];
  const float d2  = red[0][3] + red[1][3] + red[2][3] + red[3][3];
  const float e0 = lrelu(ca1 + d0), e1 = lrelu(ca1 + d1), e2 = lrelu(ca1 + d2);
  const float mm = fmaxf(e0, fmaxf(e1, e2));
  const float x0 = __expf(e0 - mm), x1 = __expf(e1 - mm), x2 = __expf(e2 - mm);
  const float invs = 1.f / (x0 + x1 + x2);
  pooled[tid] = (x0 * cw + x1 * l0 + x2 * l1) * invs;
  __syncthreads();
  {  // dense head: f-dim split 2-way, 8 accumulators
    const int o = tid & (PP - 1), half = tid >> 7;
    const float* dWc = dW + (half * 128) * PP + o;
    const float* pl = &pooled[half * 128];
    float a0 = 0.f, b1 = 0.f, b2 = 0.f, b3 = 0.f;
    float a4 = 0.f, a5 = 0.f, a6 = 0.f, a7 = 0.f;
#pragma unroll
    for (int f = 0; f < 128; f += 8) {
      a0 = fmaf(pl[f + 0], dWc[(f + 0) * PP], a0);
      b1 = fmaf(pl[f + 1], dWc[(f + 1) * PP], b1);
      b2 = fmaf(pl[f + 2], dWc[(f + 2) * PP], b2);
      b3 = fmaf(pl[f + 3], dWc[(f + 3) * PP], b3);
      a4 = fmaf(pl[f + 4], dWc[(f + 4) * PP], a4);
      a5 = fmaf(pl[f + 5], dWc[(f + 5) * PP], a5);
      a6 = fmaf(pl[f + 6], dWc[(f + 6) * PP], a6);
      a7 = fmaf(pl[f + 7], dWc[(f + 7) * PP], a7);
    }
    finp[half][o] = ((a0 + b1) + (b2 + b3)) + ((a4 + a5) + (a6 + a7));
  }
  __syncthreads();
  if (tid < PP) out[b * PP + tid] = elu_(db[tid] + finp[0][tid] + finp[1][tid]);
}

extern "C" void kernel_launch(void* const* d_in, const int* in_sizes, int n_in,
                              void* d_out, int out_size, void* d_ws, size_t ws_size,
                              hipStream_t stream) {
  const float* x     = (const float*)d_in[0];
  const float* E     = (const float*)d_in[1];
  const float* W     = (const float*)d_in[2];
  const float* a1    = (const float*)d_in[3];
  const float* a2    = (const float*)d_in[4];
  const float* cls_w = (const float*)d_in[5];
  const float* ac1   = (const float*)d_in[6];
  const float* ac2   = (const float*)d_in[7];
  const float* dW    = (const float*)d_in[8];
  const float* db    = (const float*)d_in[9];
  float* out = (float*)d_out;

  float* ws  = (float*)d_ws;
  float* EW  = ws + OFF_EW;
  float* F1  = ws + OFF_F1;
  float* F2  = ws + OFF_F2;
  float* LAT = ws + OFF_LAT;
  int*   CNT = (int*)(ws + OFF_CNT);
  int*   S   = (int*)(ws + OFF_S);

  k_pre<<<2008, 256, 0, stream>>>(E, W, a1, a2, x, EW, F1, F2, S, CNT, LAT);
  k_attn<<<dim3(KK * BB, YB, HH), 256, 0, stream>>>(EW, F1, F2, S, CNT, LAT);
  k_final<<<BB, 256, 0, stream>>>(cls_w, ac1, ac2, dW, db, LAT, out);
}

// Round 14
// 30.034 us; speedup vs baseline: 1.1343x; 1.0032x over previous
//
#include <hip/hip_runtime.h>
#include <hip/hip_bf16.h>

// Problem constants (from reference)
#define KK 2
#define BB 4
#define VV 2000
#define DD 64
#define HH 4
#define DHH 64
#define PP 128
#define ALPHA_ 0.2f

// k_attn geometry (R5/R13-validated): 32-row tiles, grid (8,8,4) = 256 blocks
#define RPB 32                // rows per block-tile (2 MFMA row-tiles)
#define YB  8                 // y-blocks (tiles strided by YB)

typedef __attribute__((ext_vector_type(8))) short bf16x8;
typedef __attribute__((ext_vector_type(4))) float f32x4;

__device__ __forceinline__ float lrelu(float z) { return fmaxf(z, ALPHA_ * z); }
__device__ __forceinline__ float elu_(float z)  { return z > 0.f ? z : expm1f(z); }
__device__ __forceinline__ short f2bf(float f) {
  __hip_bfloat16 h = __float2bfloat16(f);
  return *reinterpret_cast<short*>(&h);
}

// ---------------------------------------------------------------------------
// Workspace layout (float offsets):
//   EWb [H][V][DH] bf16 : 0       (256000 f = 512000 ushort)
//   F12 [H][V] float2   : 256000  (16000)
//   LAT [K][B][256]     : 272000  (2048)
//   CNT (int)[8]        : 274048  (8)
//   S   (int)[K*B][V]   : 274056  (16000)
// ---------------------------------------------------------------------------
#define OFF_EWB  0
#define OFF_F12  256000
#define OFF_LAT  272000
#define OFF_CNT  274048
#define OFF_S    274056

// ---- kernel 0 (fused): EWb/F12 precompute (present rows only) + compaction
__global__ __launch_bounds__(256) void k_pre(
    const float* __restrict__ E, const float* __restrict__ W,
    const float* __restrict__ a1, const float* __restrict__ a2,
    const float* __restrict__ x,
    unsigned short* __restrict__ EWb, float2* __restrict__ F12,
    int* __restrict__ S, int* __restrict__ cnt, float* __restrict__ lat) {
  const int bid = blockIdx.x;
  const int wave = threadIdx.x >> 6, lane = threadIdx.x & 63;
  if (bid < 2000) {
    const int h = bid / 500;                 // h-major: W_h stays L1-hot
    const int v = (bid % 500) * 4 + wave;
    bool pres = false;                       // skip rows absent in all slices
#pragma unroll
    for (int kb = 0; kb < KK * BB; ++kb) pres |= (x[kb * VV + v] > 0.f);
    if (!pres) return;
    const float* Wh = W + h * DD * DHH;
    const float* Ev = E + v * DD;
    float acc = 0.f;
#pragma unroll 8
    for (int d = 0; d < DD; ++d) acc = fmaf(Ev[d], Wh[d * DHH + lane], acc);
    // bf16 rounding here == the f2bf k_attn used to apply on read: bit-exact
    EWb[(size_t)(h * VV + v) * DHH + lane] = (unsigned short)f2bf(acc);
    float r1 = acc * a1[h * DHH + lane];
    float r2 = acc * a2[h * DHH + lane];
#pragma unroll
    for (int s = 32; s; s >>= 1) { r1 += __shfl_xor(r1, s); r2 += __shfl_xor(r2, s); }
    if (lane == 0) F12[h * VV + v] = make_float2(r1, r2);
  } else {
    if (wave != 0) return;
    const int kb = bid - 2000;  // 0..7
    for (int i = lane; i < 256; i += 64) lat[kb * 256 + i] = 0.f;
    const float* xr = x + kb * VV;
    int base = 0;
    for (int t = 0; t * 64 < VV; ++t) {
      const int v = t * 64 + lane;
      const bool f = (v < VV) && (xr[v] > 0.f);
      const unsigned long long m = __ballot(f);
      if (f) S[kb * VV + base + __popcll(m & ((1ull << lane) - 1ull))] = v;
      base += __popcll(m);
    }
    if (lane == 0) cnt[kb] = base;
  }
}

// ---- kernel 1: attention rows via MFMA (R13 structure; bf16 EW gathers) ---
// block = (kb, tile-stride y, h); 32 rows per tile. Softmax stats in f32
// (wave w owns rows 8w..8w+8), then PV as bf16 MFMA 16x16x32:
//   A = P (computed per-lane in registers), B = EWb columns (2B L2 gathers).
__global__ __launch_bounds__(256) void k_attn(
    const unsigned short* __restrict__ EWb, const float2* __restrict__ F12,
    const int* __restrict__ S, const int* __restrict__ cnt,
    float* __restrict__ lat) {
  __shared__ int   Sl[2048];     // compacted indices (padded)
  __shared__ float G1l[2048];    // gathered F1
  __shared__ float G2l[2048];    // gathered F2 (padded with 0)
  __shared__ float SF1[RPB], SM[RPB], SIV[RPB];  // per-tile row stats

  const int kb = blockIdx.x;     // 0..7
  const int h  = blockIdx.z;     // 0..3
  const int tid = threadIdx.x;
  const int wave = tid >> 6, lane = tid & 63;
  const int n = cnt[kb];
  const int nt = (n + RPB - 1) / RPB;
  if ((int)blockIdx.y >= nt) return;
  const int nup = (n + 31) & ~31;

  const int* Skb = S + kb * VV;
  const float2* F12h = F12 + h * VV;
  const unsigned short* EWh = EWb + (size_t)h * VV * DHH;

  // stage indices + gathered F1/F2 once per block (one 8B gather stream)
  for (int j = tid; j < nup; j += 256) {
    const int v = (j < n) ? Skb[j] : Skb[0];
    Sl[j] = v;
    const float2 f12 = F12h[v];
    G1l[j] = f12.x;
    G2l[j] = (j < n) ? f12.y : 0.f;
  }
  __syncthreads();

  const int col = (wave << 4) | (lane & 15);   // output/B column
  const int q   = lane >> 4;                   // K-quarter
  const unsigned short* EWcol = EWh + col;

  for (int tile = blockIdx.y; tile < nt; tile += YB) {
    // ---- softmax stats: wave owns rows r0w..r0w+8 ----
    const int r0w = tile * RPB + wave * 8;
    bool act[8]; float f1r[8];
#pragma unroll
    for (int i = 0; i < 8; ++i) {
      const int r = r0w + i;
      act[i] = r < n;
      f1r[i] = G1l[act[i] ? r : 0];
    }
    float m[8];
#pragma unroll
    for (int i = 0; i < 8; ++i) m[i] = -3.4e38f;
    for (int jb = lane; jb < n; jb += 64) {
      const float g = G2l[jb];
#pragma unroll
      for (int i = 0; i < 8; ++i) m[i] = fmaxf(m[i], lrelu(f1r[i] + g));
    }
#pragma unroll
    for (int s = 32; s; s >>= 1)
#pragma unroll
      for (int i = 0; i < 8; ++i) m[i] = fmaxf(m[i], __shfl_xor(m[i], s));
    float sm[8];
#pragma unroll
    for (int i = 0; i < 8; ++i) sm[i] = 0.f;
    for (int jb = lane; jb < n; jb += 64) {
      const float g = G2l[jb];
#pragma unroll
      for (int i = 0; i < 8; ++i) sm[i] += __expf(lrelu(f1r[i] + g) - m[i]);
    }
#pragma unroll
    for (int s = 32; s; s >>= 1)
#pragma unroll
      for (int i = 0; i < 8; ++i) sm[i] += __shfl_xor(sm[i], s);

    __syncthreads();  // previous tile's MFMA phase done reading stats
    if (lane == 0) {
#pragma unroll
      for (int i = 0; i < 8; ++i) {
        SF1[wave * 8 + i] = f1r[i];
        SM[wave * 8 + i]  = m[i];
        SIV[wave * 8 + i] = act[i] ? (1.f / sm[i]) : 0.f;
      }
    }
    __syncthreads();  // stats visible to all waves

    // ---- MFMA PV phase: wave w computes cols 16w..16w+16, rows 0..31 ----
    const int rl = lane & 15;
    const float f1a = SF1[rl],      ma = SM[rl],      ia = SIV[rl];
    const float f1b = SF1[16 + rl], mb = SM[16 + rl], ib = SIV[16 + rl];
    f32x4 acc0 = {0.f, 0.f, 0.f, 0.f}, acc1 = {0.f, 0.f, 0.f, 0.f};
    for (int kc = 0; kc < nup; kc += 32) {
      const int kq = kc + q * 8;
      const int4 va = *reinterpret_cast<const int4*>(&Sl[kq]);
      const int4 vb = *reinterpret_cast<const int4*>(&Sl[kq + 4]);
      const float4 ga = *reinterpret_cast<const float4*>(&G2l[kq]);
      const float4 gb = *reinterpret_cast<const float4*>(&G2l[kq + 4]);
      bf16x8 Bf;
      Bf[0] = (short)EWcol[(size_t)va.x * DHH];
      Bf[1] = (short)EWcol[(size_t)va.y * DHH];
      Bf[2] = (short)EWcol[(size_t)va.z * DHH];
      Bf[3] = (short)EWcol[(size_t)va.w * DHH];
      Bf[4] = (short)EWcol[(size_t)vb.x * DHH];
      Bf[5] = (short)EWcol[(size_t)vb.y * DHH];
      Bf[6] = (short)EWcol[(size_t)vb.z * DHH];
      Bf[7] = (short)EWcol[(size_t)vb.w * DHH];
      const float g[8] = {ga.x, ga.y, ga.z, ga.w, gb.x, gb.y, gb.z, gb.w};
      float pa[8], pb[8];
#pragma unroll
      for (int t = 0; t < 8; ++t) {
        const float gt = g[t];
        pa[t] = __expf(lrelu(f1a + gt) - ma) * ia;
        pb[t] = __expf(lrelu(f1b + gt) - mb) * ib;
      }
      if (kc + 32 > n) {  // K-tail: zero out-of-range columns
#pragma unroll
        for (int t = 0; t < 8; ++t)
          if (kq + t >= n) { pa[t] = 0.f; pb[t] = 0.f; }
      }
      bf16x8 A0, A1;
#pragma unroll
      for (int t = 0; t < 8; ++t) {
        A0[t] = f2bf(pa[t]);
        A1[t] = f2bf(pb[t]);
      }
      acc0 = __builtin_amdgcn_mfma_f32_16x16x32_bf16(A0, Bf, acc0, 0, 0, 0);
      acc1 = __builtin_amdgcn_mfma_f32_16x16x32_bf16(A1, Bf, acc1, 0, 0, 0);
    }
    // ---- epilogue: lat[col] = max(0, max_rows elu(out)) ----
    float vmax = -3.4e38f;
#pragma unroll
    for (int r = 0; r < 4; ++r) {
      const int row0 = tile * RPB + (q << 2) + r;
      const int row1 = row0 + 16;
      if (row0 < n) vmax = fmaxf(vmax, acc0[r]);
      if (row1 < n) vmax = fmaxf(vmax, acc1[r]);
    }
    if (vmax > 0.f)
      atomicMax(reinterpret_cast<int*>(&lat[kb * 256 + h * DHH + col]),
                __float_as_int(vmax));
  }
}

// ---- kernel 2: latent pooling + dense head; one block per batch -----------
// 8-accumulator / 2-way f-split matvec (~32 loads in flight, depth 128).
__global__ __launch_bounds__(256) void k_final(
    const float* __restrict__ cls_w, const float* __restrict__ ac1,
    const float* __restrict__ ac2, const float* __restrict__ dW,
    const float* __restrict__ db, const float* __restrict__ lat,
    float* __restrict__ out) {
  const int b = blockIdx.x;
  const int tid = threadIdx.x;  // 256
  const int lane = tid & 63, wave = tid >> 6;
  __shared__ float pooled[256];
  __shared__ float finp[2][PP];
  __shared__ float red[4][4];
  const float cw = cls_w[tid];
  const float l0 = lat[(0 * BB + b) * 256 + tid];
  const float l1 = lat[(1 * BB + b) * 256 + tid];
  float t0 = cw * ac1[tid];
  float t1 = cw * ac2[tid];
  float t2 = l0 * ac2[tid];
  float t3 = l1 * ac2[tid];
#pragma unroll
  for (int s = 32; s; s >>= 1) {
    t0 += __shfl_xor(t0, s); t1 += __shfl_xor(t1, s);
    t2 += __shfl_xor(t2, s); t3 += __shfl_xor(t3, s);
  }
  if (lane == 0) { red[wave][0] = t0; red[wave][1] = t1; red[wave][2] = t2; red[wave][3] = t3; }
  __syncthreads();
  const float ca1 = red[0][0] + red[1][0] + red[2][0] + red[3][0];
  const float d0  = red[0][1] + red[1][1] + red[2][1] + red[3][1];
  const float d1  = red[0][2] + red[1][2] + red[2][2] + red[3][2];
  const float d2  = red[0][3] + red[1][3] + red[2][3] + red[3][3];
  const float e0 = lrelu(ca1 + d0), e1 = lrelu(ca1 + d1), e2 = lrelu(ca1 + d2);
  const float mm = fmaxf(e0, fmaxf(e1, e2));
  const float x0 = __expf(e0 - mm), x1 = __expf(e1 - mm), x2 = __expf(e2 - mm);
  const float invs = 1.f / (x0 + x1 + x2);
  pooled[tid] = (x0 * cw + x1 * l0 + x2 * l1) * invs;
  __syncthreads();
  {  // dense head: f-dim split 2-way, 8 accumulators
    const int o = tid & (PP - 1), half = tid >> 7;
    const float* dWc = dW + (half * 128) * PP + o;
    const float* pl = &pooled[half * 128];
    float a0 = 0.f, b1 = 0.f, b2 = 0.f, b3 = 0.f;
    float a4 = 0.f, a5 = 0.f, a6 = 0.f, a7 = 0.f;
#pragma unroll
    for (int f = 0; f < 128; f += 8) {
      a0 = fmaf(pl[f + 0], dWc[(f + 0) * PP], a0);
      b1 = fmaf(pl[f + 1], dWc[(f + 1) * PP], b1);
      b2 = fmaf(pl[f + 2], dWc[(f + 2) * PP], b2);
      b3 = fmaf(pl[f + 3], dWc[(f + 3) * PP], b3);
      a4 = fmaf(pl[f + 4], dWc[(f + 4) * PP], a4);
      a5 = fmaf(pl[f + 5], dWc[(f + 5) * PP], a5);
      a6 = fmaf(pl[f + 6], dWc[(f + 6) * PP], a6);
      a7 = fmaf(pl[f + 7], dWc[(f + 7) * PP], a7);
    }
    finp[half][o] = ((a0 + b1) + (b2 + b3)) + ((a4 + a5) + (a6 + a7));
  }
  __syncthreads();
  if (tid < PP) out[b * PP + tid] = elu_(db[tid] + finp[0][tid] + finp[1][tid]);
}

extern "C" void kernel_launch(void* const* d_in, const int* in_sizes, int n_in,
                              void* d_out, int out_size, void* d_ws, size_t ws_size,
                              hipStream_t stream) {
  const float* x     = (const float*)d_in[0];
  const float* E     = (const float*)d_in[1];
  const float* W     = (const float*)d_in[2];
  const float* a1    = (const float*)d_in[3];
  const float* a2    = (const float*)d_in[4];
  const float* cls_w = (const float*)d_in[5];
  const float* ac1   = (const float*)d_in[6];
  const float* ac2   = (const float*)d_in[7];
  const float* dW    = (const float*)d_in[8];
  const float* db    = (const float*)d_in[9];
  float* out = (float*)d_out;

  float* ws  = (float*)d_ws;
  unsigned short* EWB = (unsigned short*)(ws + OFF_EWB);
  float2* F12 = (float2*)(ws + OFF_F12);
  float* LAT = ws + OFF_LAT;
  int*   CNT = (int*)(ws + OFF_CNT);
  int*   S   = (int*)(ws + OFF_S);

  k_pre<<<2008, 256, 0, stream>>>(E, W, a1, a2, x, EWB, F12, S, CNT, LAT);
  k_attn<<<dim3(KK * BB, YB, HH), 256, 0, stream>>>(EWB, F12, S, CNT, LAT);
  k_final<<<BB, 256, 0, stream>>>(cls_w, ac1, ac2, dW, db, LAT, out);
}